// Round 5
// baseline (1900.059 us; speedup 1.0000x reference)
//
#include <hip/hip_runtime.h>

#define HP 1.57079632679489662f

typedef float f32x4 __attribute__((ext_vector_type(4)));

__device__ __forceinline__ unsigned short f2bf(float f) {
  unsigned int u = __builtin_bit_cast(unsigned int, f);
  u += 0x7fffu + ((u >> 16) & 1u);
  return (unsigned short)(u >> 16);
}
__device__ __forceinline__ float bf2f(unsigned short h) {
  unsigned int u = ((unsigned int)h) << 16;
  return __builtin_bit_cast(float, u);
}

// ws layout:
//   int  meta[64]         @ 0    : meta[0]=n_edges, meta[1+2e],meta[2+2e]=(i,j)
//   bf16 Ub[8][512][32]   @ 4096 : chunk ks holds k in [32ks,32ks+32); row m: 2r=Re,2r+1=Im
//                                  within row m (64B), 8-elem group sub at 16B slot (sub+(m>>1))&3

// ---------------- K0: edge thresholding, exact numpy f64 semantics ----------------
__global__ void prep_kernel(const float* __restrict__ coup, void* __restrict__ wsv) {
  if (threadIdx.x != 0) return;
  int* meta = (int*)wsv;
  double mn = 1e300, mx = -1e300;
  for (int k = 0; k < 64; k++) {
    double v = (double)coup[k];
    mn = v < mn ? v : mn;
    mx = v > mx ? v : mx;
  }
  int cnt = 0;
  for (int i = 0; i < 8; i++)
    for (int j = i + 1; j < 8; j++) {
      double cn = ((double)coup[i * 8 + j] - mn) / (mx - mn);
      if (cn > 0.5) {
        meta[1 + 2 * cnt] = i;
        meta[2 + 2 * cnt] = j;
        cnt++;
      }
    }
  meta[0] = cnt;
}

// ---------------- K1: LITERAL gate-by-gate basis-column simulation (proven R3) -------
__global__ __launch_bounds__(256) void build_u_kernel(const float* __restrict__ wt,
                                                      const float* __restrict__ coup,
                                                      void* __restrict__ wsv) {
  const int* meta = (const int*)wsv;
  unsigned char* Ub = (unsigned char*)wsv + 4096;
  const int c = blockIdx.x;
  const int tid = threadIdx.x;

  __shared__ float2 s[256];
  s[tid] = make_float2(tid == c ? 1.f : 0.f, 0.f);
  __syncthreads();

  auto RZg = [&](float t, int p) {
    float cz = cosf(0.5f * t), sz = sinf(0.5f * t);
    float2 a = s[tid];
    float2 r;
    if ((tid >> p) & 1) r = make_float2(cz * a.x - sz * a.y, cz * a.y + sz * a.x);
    else                r = make_float2(cz * a.x + sz * a.y, cz * a.y - sz * a.x);
    s[tid] = r;
    __syncthreads();
  };
  auto RYg = [&](float t, int p) {
    float cy = cosf(0.5f * t), sy = sinf(0.5f * t);
    int m = 1 << p;
    float2 a0 = s[tid & ~m];
    float2 a1 = s[tid | m];
    __syncthreads();
    float2 r;
    if (tid & m) r = make_float2(sy * a0.x + cy * a1.x, sy * a0.y + cy * a1.y);
    else         r = make_float2(cy * a0.x - sy * a1.x, cy * a0.y - sy * a1.y);
    s[tid] = r;
    __syncthreads();
  };
  auto RXg = [&](float t, int p) {
    float cx = cosf(0.5f * t), sx = sinf(0.5f * t);
    int m = 1 << p;
    float2 a0 = s[tid & ~m];
    float2 a1 = s[tid | m];
    __syncthreads();
    float2 r;
    if (tid & m) r = make_float2(sx * a0.y + cx * a1.x, -sx * a0.x + cx * a1.y);
    else         r = make_float2(cx * a0.x + sx * a1.y, cx * a0.y - sx * a1.x);
    s[tid] = r;
    __syncthreads();
  };
  auto CN = [&](int pc, int pt) {
    int src = ((tid >> pc) & 1) ? (tid ^ (1 << pt)) : tid;
    float2 v = s[src];
    __syncthreads();
    s[tid] = v;
    __syncthreads();
  };
  auto SW = [&](int p1, int p2) {
    int b1 = (tid >> p1) & 1, b2 = (tid >> p2) & 1;
    int src = (b1 != b2) ? (tid ^ (1 << p1) ^ (1 << p2)) : tid;
    float2 v = s[src];
    __syncthreads();
    s[tid] = v;
    __syncthreads();
  };

  for (int w = 0; w < 8; w++) {
    int p = 7 - w;
    RXg(wt[w], p);
    RYg(wt[8 + w], p);
    RZg(wt[16 + w], p);
  }

  for (int i = 0; i < 8; i++)
    for (int j = i + 1; j < 8; j++) {
      float t = coup[i * 8 + j];
      float ch = cosf(0.5f * t), sn = sinf(0.5f * t);
      int mask = (1 << (7 - i)) | (1 << (7 - j));
      float2 a = s[tid];
      float2 b = s[tid ^ mask];
      __syncthreads();
      s[tid] = make_float2(ch * a.x + sn * b.y, ch * a.y - sn * b.x);
      __syncthreads();
    }

  int ne = meta[0];
  for (int e = 0; e < ne; e++) {
    int i = meta[1 + 2 * e], jj = meta[2 + 2 * e];
    int pi = 7 - i, pj = 7 - jj;
    bool nonadj = (jj - i) != 1;
    const float* pw = wt + 24 + 6 * e;
    if (nonadj) SW(pi, pj);
    RZg(-HP, pj);
    CN(pj, pi);
    RZg(pw[0], pi);
    RYg(pw[1], pj);
    CN(pi, pj);
    RYg(pw[2], pj);
    CN(pj, pi);
    RZg(HP, pi);
    RZg(-HP, pj);
    CN(pj, pi);
    RZg(pw[3], pi);
    RYg(pw[4], pj);
    CN(pi, pj);
    RYg(pw[5], pj);
    if (nonadj) SW(pi, pj);
  }

  // write column c as bf16 into the pre-swizzled chunk image
  {
    int ks = c >> 5, kc = c & 31;
    int sub = kc >> 3, j2 = kc & 7;
    int p = (sub + tid) & 3;  // m>>1 == tid for both rows
    unsigned char* base = Ub + (size_t)ks * 32768 + (size_t)(2 * tid) * 64 + p * 16 + j2 * 2;
    *(unsigned short*)(base)      = f2bf(s[tid].x);
    *(unsigned short*)(base + 64) = f2bf(s[tid].y);
  }
}

// ---------------- K2: IDENTICAL data path to R4, MFMA replaced by fp32 emulation ------
// LDS: [0,32768)      psi bf16 [64][256], XOR-swizzled (byte ^= (row&7)<<4)
//      [32768,65536)  U chunk image (linear copy; rotation pre-applied)
// acc[mf][nf][reg] += sum_k U[m(reg)][k] * psi[n][k]  — exactly what MFMA should produce
// under the assumed layouts. Same epilogue as R4.
__global__ __launch_bounds__(512) void gemm_emul(const float* __restrict__ x,
                                                 const void* __restrict__ wsv,
                                                 float* __restrict__ out) {
  const unsigned char* Ub = (const unsigned char*)wsv + 4096;
  __shared__ __align__(16) unsigned char smem[65536];
  const int AOFF = 32768;

  const int tid = threadIdx.x;
  const int blk = blockIdx.x;
  const int wv = tid >> 6;
  const int lane = tid & 63;
  const int lm = lane & 15;
  const int lg = lane >> 4;

  // ---- prologue: identical to R4 ----
  {
    const int rl = tid >> 3;
    const int seg = tid & 7;
    const float4* xs = (const float4*)(x + (size_t)(blk * 64 + rl) * 256 + seg * 32);
    float4 v[8];
    float ss = 0.f;
#pragma unroll
    for (int i = 0; i < 8; i++) {
      v[i] = xs[i];
      ss += v[i].x * v[i].x + v[i].y * v[i].y + v[i].z * v[i].z + v[i].w * v[i].w;
    }
    ss += __shfl_xor(ss, 1);
    ss += __shfl_xor(ss, 2);
    ss += __shfl_xor(ss, 4);
    float inv = 1.0f / sqrtf(ss);
#pragma unroll
    for (int u = 0; u < 4; u++) {
      unsigned short h[8];
#pragma unroll
      for (int k = 0; k < 8; k++) {
        float f = ((const float*)v)[u * 8 + k] * inv;
        h[k] = f2bf(f);
      }
      uint4 pack;
      pack.x = (unsigned)h[0] | ((unsigned)h[1] << 16);
      pack.y = (unsigned)h[2] | ((unsigned)h[3] << 16);
      pack.z = (unsigned)h[4] | ((unsigned)h[5] << 16);
      pack.w = (unsigned)h[6] | ((unsigned)h[7] << 16);
      int byte = (rl * 512 + seg * 64 + u * 16) ^ ((rl & 7) << 4);
      *reinterpret_cast<uint4*>(&smem[byte]) = pack;
    }
  }

  f32x4 acc[4][4] = {};

  // ---- K loop: 8 steps of BK=32, staging identical to R4 ----
  for (int ks = 0; ks < 8; ks++) {
    {
      const uint4* src = (const uint4*)(Ub + (size_t)ks * 32768);
#pragma unroll
      for (int g = 0; g < 4; g++)
        *reinterpret_cast<uint4*>(&smem[AOFF + g * 8192 + tid * 16]) = src[g * 512 + tid];
    }
    __syncthreads();

    // ---- EMULATED MFMA: same addresses, fp32 dot products ----
#pragma unroll
    for (int mf = 0; mf < 4; mf++) {
#pragma unroll
      for (int rr = 0; rr < 4; rr++) {
        const int m = wv * 64 + mf * 16 + 4 * lg + rr;  // D row this acc slot maps to
        float urow[32];
#pragma unroll
        for (int sub = 0; sub < 4; sub++) {
          int p = (sub + (m >> 1)) & 3;
          uint4 raw = *reinterpret_cast<const uint4*>(&smem[AOFF + m * 64 + p * 16]);
          const unsigned* w = (const unsigned*)&raw;
#pragma unroll
          for (int h = 0; h < 4; h++) {
            urow[sub * 8 + 2 * h]     = bf2f((unsigned short)(w[h] & 0xffffu));
            urow[sub * 8 + 2 * h + 1] = bf2f((unsigned short)(w[h] >> 16));
          }
        }
#pragma unroll
        for (int nf = 0; nf < 4; nf++) {
          const int n = nf * 16 + lm;
          float dot = 0.f;
#pragma unroll
          for (int sub = 0; sub < 4; sub++) {
            int byte = (n * 512 + ks * 64 + sub * 16) ^ ((n & 7) << 4);
            uint4 praw = *reinterpret_cast<const uint4*>(&smem[byte]);
            const unsigned* pw = (const unsigned*)&praw;
#pragma unroll
            for (int h = 0; h < 4; h++) {
              dot = fmaf(urow[sub * 8 + 2 * h],     bf2f((unsigned short)(pw[h] & 0xffffu)), dot);
              dot = fmaf(urow[sub * 8 + 2 * h + 1], bf2f((unsigned short)(pw[h] >> 16)),     dot);
            }
          }
          acc[mf][nf][rr] += dot;
        }
      }
    }
    __syncthreads();
  }

  // ---- epilogue: identical to R4 ----
  float pq[4][8];
#pragma unroll
  for (int nf = 0; nf < 4; nf++) {
    float T = 0.f, S7 = 0.f, S4 = 0.f, S3 = 0.f;
#pragma unroll
    for (int mf = 0; mf < 4; mf++) {
      f32x4 a = acc[mf][nf];
      float p0 = a[0] * a[0] + a[1] * a[1];
      float p1 = a[2] * a[2] + a[3] * a[3];
      float sp = p0 + p1, d = p0 - p1;
      T += sp;
      S7 += d;
      S4 += (mf & 1) ? -sp : sp;
      S3 += (mf & 2) ? -sp : sp;
    }
    pq[nf][7] = S7;
    pq[nf][6] = (lg & 1) ? -T : T;
    pq[nf][5] = (lg & 2) ? -T : T;
    pq[nf][4] = S4;
    pq[nf][3] = S3;
    pq[nf][2] = (wv & 1) ? -T : T;
    pq[nf][1] = (wv & 2) ? -T : T;
    pq[nf][0] = (wv & 4) ? -T : T;
  }
#pragma unroll
  for (int nf = 0; nf < 4; nf++)
#pragma unroll
    for (int k = 0; k < 8; k++) {
      pq[nf][k] += __shfl_xor(pq[nf][k], 16);
      pq[nf][k] += __shfl_xor(pq[nf][k], 32);
    }

  float* part = (float*)smem;  // [8][64][8]
  if (lg == 0) {
#pragma unroll
    for (int nf = 0; nf < 4; nf++) {
      float* dst = part + (wv * 64 + nf * 16 + lm) * 8;
#pragma unroll
      for (int k = 0; k < 8; k++) dst[k] = pq[nf][k];
    }
  }
  __syncthreads();
  {
    int b = tid >> 3, q = tid & 7;
    float v = 0.f;
#pragma unroll
    for (int w2 = 0; w2 < 8; w2++) v += part[(w2 * 64 + b) * 8 + q];
    out[(size_t)(blk * 64 + b) * 8 + q] = v;
  }
}

extern "C" void kernel_launch(void* const* d_in, const int* in_sizes, int n_in,
                              void* d_out, int out_size, void* d_ws, size_t ws_size,
                              hipStream_t stream) {
  const float* x    = (const float*)d_in[0];
  const float* wt   = (const float*)d_in[1];
  const float* coup = (const float*)d_in[2];
  float* out = (float*)d_out;

  prep_kernel<<<1, 1, 0, stream>>>(coup, d_ws);
  build_u_kernel<<<256, 256, 0, stream>>>(wt, coup, d_ws);
  gemm_emul<<<1024, 512, 0, stream>>>(x, d_ws, out);
}

// Round 6
// 98.632 us; speedup vs baseline: 19.2642x; 19.2642x over previous
//
#include <hip/hip_runtime.h>

#define HP 1.57079632679489662f

typedef float f32x4 __attribute__((ext_vector_type(4)));
typedef short sh4 __attribute__((ext_vector_type(4)));

__device__ __forceinline__ unsigned short f2bf(float f) {
  unsigned int u = __builtin_bit_cast(unsigned int, f);
  u += 0x7fffu + ((u >> 16) & 1u);
  return (unsigned short)(u >> 16);
}

// ws layout:
//   int  meta[64]         @ 0    : meta[0]=n_edges, meta[1+2e],meta[2+2e]=(i,j)
//   bf16 Ub[8][512][32]   @ 4096 : chunk ks holds k in [32ks,32ks+32); row m: 2r=Re,2r+1=Im
//                                  within row m (64B), 8-elem group sub at 16B slot (sub+(m>>1))&3

// ---------------- K0: edge thresholding, exact numpy f64 semantics ----------------
__global__ void prep_kernel(const float* __restrict__ coup, void* __restrict__ wsv) {
  if (threadIdx.x != 0) return;
  int* meta = (int*)wsv;
  double mn = 1e300, mx = -1e300;
  for (int k = 0; k < 64; k++) {
    double v = (double)coup[k];
    mn = v < mn ? v : mn;
    mx = v > mx ? v : mx;
  }
  int cnt = 0;
  for (int i = 0; i < 8; i++)
    for (int j = i + 1; j < 8; j++) {
      double cn = ((double)coup[i * 8 + j] - mn) / (mx - mn);
      if (cn > 0.5) {
        meta[1 + 2 * cnt] = i;
        meta[2 + 2 * cnt] = j;
        cnt++;
      }
    }
  meta[0] = cnt;
}

// ---------------- K1: LITERAL gate-by-gate basis-column simulation (proven R3/R5) -----
__global__ __launch_bounds__(256) void build_u_kernel(const float* __restrict__ wt,
                                                      const float* __restrict__ coup,
                                                      void* __restrict__ wsv) {
  const int* meta = (const int*)wsv;
  unsigned char* Ub = (unsigned char*)wsv + 4096;
  const int c = blockIdx.x;
  const int tid = threadIdx.x;

  __shared__ float2 s[256];
  s[tid] = make_float2(tid == c ? 1.f : 0.f, 0.f);
  __syncthreads();

  auto RZg = [&](float t, int p) {
    float cz = cosf(0.5f * t), sz = sinf(0.5f * t);
    float2 a = s[tid];
    float2 r;
    if ((tid >> p) & 1) r = make_float2(cz * a.x - sz * a.y, cz * a.y + sz * a.x);
    else                r = make_float2(cz * a.x + sz * a.y, cz * a.y - sz * a.x);
    s[tid] = r;
    __syncthreads();
  };
  auto RYg = [&](float t, int p) {
    float cy = cosf(0.5f * t), sy = sinf(0.5f * t);
    int m = 1 << p;
    float2 a0 = s[tid & ~m];
    float2 a1 = s[tid | m];
    __syncthreads();
    float2 r;
    if (tid & m) r = make_float2(sy * a0.x + cy * a1.x, sy * a0.y + cy * a1.y);
    else         r = make_float2(cy * a0.x - sy * a1.x, cy * a0.y - sy * a1.y);
    s[tid] = r;
    __syncthreads();
  };
  auto RXg = [&](float t, int p) {
    float cx = cosf(0.5f * t), sx = sinf(0.5f * t);
    int m = 1 << p;
    float2 a0 = s[tid & ~m];
    float2 a1 = s[tid | m];
    __syncthreads();
    float2 r;
    if (tid & m) r = make_float2(sx * a0.y + cx * a1.x, -sx * a0.x + cx * a1.y);
    else         r = make_float2(cx * a0.x + sx * a1.y, cx * a0.y - sx * a1.x);
    s[tid] = r;
    __syncthreads();
  };
  auto CN = [&](int pc, int pt) {
    int src = ((tid >> pc) & 1) ? (tid ^ (1 << pt)) : tid;
    float2 v = s[src];
    __syncthreads();
    s[tid] = v;
    __syncthreads();
  };
  auto SW = [&](int p1, int p2) {
    int b1 = (tid >> p1) & 1, b2 = (tid >> p2) & 1;
    int src = (b1 != b2) ? (tid ^ (1 << p1) ^ (1 << p2)) : tid;
    float2 v = s[src];
    __syncthreads();
    s[tid] = v;
    __syncthreads();
  };

  for (int w = 0; w < 8; w++) {
    int p = 7 - w;
    RXg(wt[w], p);
    RYg(wt[8 + w], p);
    RZg(wt[16 + w], p);
  }

  for (int i = 0; i < 8; i++)
    for (int j = i + 1; j < 8; j++) {
      float t = coup[i * 8 + j];
      float ch = cosf(0.5f * t), sn = sinf(0.5f * t);
      int mask = (1 << (7 - i)) | (1 << (7 - j));
      float2 a = s[tid];
      float2 b = s[tid ^ mask];
      __syncthreads();
      s[tid] = make_float2(ch * a.x + sn * b.y, ch * a.y - sn * b.x);
      __syncthreads();
    }

  int ne = meta[0];
  for (int e = 0; e < ne; e++) {
    int i = meta[1 + 2 * e], jj = meta[2 + 2 * e];
    int pi = 7 - i, pj = 7 - jj;
    bool nonadj = (jj - i) != 1;
    const float* pw = wt + 24 + 6 * e;
    if (nonadj) SW(pi, pj);
    RZg(-HP, pj);
    CN(pj, pi);
    RZg(pw[0], pi);
    RYg(pw[1], pj);
    CN(pi, pj);
    RYg(pw[2], pj);
    CN(pj, pi);
    RZg(HP, pi);
    RZg(-HP, pj);
    CN(pj, pi);
    RZg(pw[3], pi);
    RYg(pw[4], pj);
    CN(pi, pj);
    RYg(pw[5], pj);
    if (nonadj) SW(pi, pj);
  }

  // write column c as bf16 into the pre-swizzled chunk image
  {
    int ks = c >> 5, kc = c & 31;
    int sub = kc >> 3, j2 = kc & 7;
    int p = (sub + tid) & 3;  // m>>1 == tid for both rows
    unsigned char* base = Ub + (size_t)ks * 32768 + (size_t)(2 * tid) * 64 + p * 16 + j2 * 2;
    *(unsigned short*)(base)      = f2bf(s[tid].x);
    *(unsigned short*)(base + 64) = f2bf(s[tid].y);
  }
}

// ---------------- K2: R5 scaffold, compute via classic v_mfma_f32_16x16x16_bf16 -------
// LDS: [0,32768)      psi bf16 [64][256], XOR-swizzled (byte ^= (row&7)<<4)
//      [32768,65536)  U chunk image (linear copy; rotation pre-applied)
// Classic layout: A lane l holds A[l&15][4*(l>>4)+i]; B lane l holds B[4*(l>>4)+i][l&15];
// D: col=lane&15, row=4*(lane>>4)+reg  (same D map the R5 emulation validated end-to-end)
__global__ __launch_bounds__(512) void gemm_mfma16(const float* __restrict__ x,
                                                   const void* __restrict__ wsv,
                                                   float* __restrict__ out) {
  const unsigned char* Ub = (const unsigned char*)wsv + 4096;
  __shared__ __align__(16) unsigned char smem[65536];
  const int AOFF = 32768;

  const int tid = threadIdx.x;
  const int blk = blockIdx.x;
  const int wv = tid >> 6;
  const int lane = tid & 63;
  const int lm = lane & 15;
  const int lg = lane >> 4;

  // ---- prologue: identical to R4/R5 ----
  {
    const int rl = tid >> 3;
    const int seg = tid & 7;
    const float4* xs = (const float4*)(x + (size_t)(blk * 64 + rl) * 256 + seg * 32);
    float4 v[8];
    float ss = 0.f;
#pragma unroll
    for (int i = 0; i < 8; i++) {
      v[i] = xs[i];
      ss += v[i].x * v[i].x + v[i].y * v[i].y + v[i].z * v[i].z + v[i].w * v[i].w;
    }
    ss += __shfl_xor(ss, 1);
    ss += __shfl_xor(ss, 2);
    ss += __shfl_xor(ss, 4);
    float inv = 1.0f / sqrtf(ss);
#pragma unroll
    for (int u = 0; u < 4; u++) {
      unsigned short h[8];
#pragma unroll
      for (int k = 0; k < 8; k++) {
        float f = ((const float*)v)[u * 8 + k] * inv;
        h[k] = f2bf(f);
      }
      uint4 pack;
      pack.x = (unsigned)h[0] | ((unsigned)h[1] << 16);
      pack.y = (unsigned)h[2] | ((unsigned)h[3] << 16);
      pack.z = (unsigned)h[4] | ((unsigned)h[5] << 16);
      pack.w = (unsigned)h[6] | ((unsigned)h[7] << 16);
      int byte = (rl * 512 + seg * 64 + u * 16) ^ ((rl & 7) << 4);
      *reinterpret_cast<uint4*>(&smem[byte]) = pack;
    }
  }

  f32x4 acc[4][4] = {};

  // ---- K loop: 8 steps of BK=32 (2 MFMAs of K=16 per step per tile) ----
  for (int ks = 0; ks < 8; ks++) {
    // staging: identical linear 32KB copy (proven R5)
    {
      const uint4* src = (const uint4*)(Ub + (size_t)ks * 32768);
#pragma unroll
      for (int g = 0; g < 4; g++)
        *reinterpret_cast<uint4*>(&smem[AOFF + g * 8192 + tid * 16]) = src[g * 512 + tid];
    }
    __syncthreads();

    sh4 a16[4][2], b16[4][2];
#pragma unroll
    for (int mf = 0; mf < 4; mf++) {
      const int m = wv * 64 + mf * 16 + lm;
#pragma unroll
      for (int h = 0; h < 2; h++) {
        // logical bytes [32h + 8lg, +8) of row m  ->  16B slot 2h+(lg>>1), sub-offset (lg&1)*8
        int p = (2 * h + (lg >> 1) + (m >> 1)) & 3;
        a16[mf][h] = __builtin_bit_cast(sh4,
            *reinterpret_cast<const uint2*>(&smem[AOFF + m * 64 + p * 16 + (lg & 1) * 8]));
      }
    }
#pragma unroll
    for (int nf = 0; nf < 4; nf++) {
      const int n = nf * 16 + lm;
#pragma unroll
      for (int h = 0; h < 2; h++) {
        int byte = (n * 512 + ks * 64 + 32 * h + 8 * lg) ^ ((n & 7) << 4);
        b16[nf][h] = __builtin_bit_cast(sh4, *reinterpret_cast<const uint2*>(&smem[byte]));
      }
    }
#pragma unroll
    for (int mf = 0; mf < 4; mf++)
#pragma unroll
      for (int nf = 0; nf < 4; nf++) {
        acc[mf][nf] = __builtin_amdgcn_mfma_f32_16x16x16bf16_1k(a16[mf][0], b16[nf][0], acc[mf][nf], 0, 0, 0);
        acc[mf][nf] = __builtin_amdgcn_mfma_f32_16x16x16bf16_1k(a16[mf][1], b16[nf][1], acc[mf][nf], 0, 0, 0);
      }
    __syncthreads();
  }

  // ---- epilogue: identical to R4/R5 (validated by R5) ----
  float pq[4][8];
#pragma unroll
  for (int nf = 0; nf < 4; nf++) {
    float T = 0.f, S7 = 0.f, S4 = 0.f, S3 = 0.f;
#pragma unroll
    for (int mf = 0; mf < 4; mf++) {
      f32x4 a = acc[mf][nf];
      float p0 = a[0] * a[0] + a[1] * a[1];
      float p1 = a[2] * a[2] + a[3] * a[3];
      float sp = p0 + p1, d = p0 - p1;
      T += sp;
      S7 += d;
      S4 += (mf & 1) ? -sp : sp;
      S3 += (mf & 2) ? -sp : sp;
    }
    pq[nf][7] = S7;
    pq[nf][6] = (lg & 1) ? -T : T;
    pq[nf][5] = (lg & 2) ? -T : T;
    pq[nf][4] = S4;
    pq[nf][3] = S3;
    pq[nf][2] = (wv & 1) ? -T : T;
    pq[nf][1] = (wv & 2) ? -T : T;
    pq[nf][0] = (wv & 4) ? -T : T;
  }
#pragma unroll
  for (int nf = 0; nf < 4; nf++)
#pragma unroll
    for (int k = 0; k < 8; k++) {
      pq[nf][k] += __shfl_xor(pq[nf][k], 16);
      pq[nf][k] += __shfl_xor(pq[nf][k], 32);
    }

  float* part = (float*)smem;  // [8][64][8]
  if (lg == 0) {
#pragma unroll
    for (int nf = 0; nf < 4; nf++) {
      float* dst = part + (wv * 64 + nf * 16 + lm) * 8;
#pragma unroll
      for (int k = 0; k < 8; k++) dst[k] = pq[nf][k];
    }
  }
  __syncthreads();
  {
    int b = tid >> 3, q = tid & 7;
    float v = 0.f;
#pragma unroll
    for (int w2 = 0; w2 < 8; w2++) v += part[(w2 * 64 + b) * 8 + q];
    out[(size_t)(blk * 64 + b) * 8 + q] = v;
  }
}

extern "C" void kernel_launch(void* const* d_in, const int* in_sizes, int n_in,
                              void* d_out, int out_size, void* d_ws, size_t ws_size,
                              hipStream_t stream) {
  const float* x    = (const float*)d_in[0];
  const float* wt   = (const float*)d_in[1];
  const float* coup = (const float*)d_in[2];
  float* out = (float*)d_out;

  prep_kernel<<<1, 1, 0, stream>>>(coup, d_ws);
  build_u_kernel<<<256, 256, 0, stream>>>(wt, coup, d_ws);
  gemm_mfma16<<<1024, 512, 0, stream>>>(x, d_ws, out);
}

// Round 7
// 72.063 us; speedup vs baseline: 26.3668x; 1.3687x over previous
//
#include <hip/hip_runtime.h>

#define HP 1.57079632679489662f

typedef float f32x4 __attribute__((ext_vector_type(4)));
typedef short sh4 __attribute__((ext_vector_type(4)));

__device__ __forceinline__ unsigned short f2bf(float f) {
  unsigned int u = __builtin_bit_cast(unsigned int, f);
  u += 0x7fffu + ((u >> 16) & 1u);
  return (unsigned short)(u >> 16);
}

// ---------------- helpers for 4x4 complex matrix absorption (G*M) ----------------
__device__ __forceinline__ void rowswap4(float (&mr)[4][4], float (&mi)[4][4], int a, int b) {
#pragma unroll
  for (int c = 0; c < 4; c++) {
    float tr = mr[a][c]; mr[a][c] = mr[b][c]; mr[b][c] = tr;
    float ti = mi[a][c]; mi[a][c] = mi[b][c]; mi[b][c] = ti;
  }
}

// RZ(t) on wire at bitpos (1 = i/MSB of pair, 0 = j/LSB): row phase e^{-it/2} (bit=0) / e^{+it/2} (bit=1)
__device__ __forceinline__ void absorb_rz(float (&mr)[4][4], float (&mi)[4][4], float t, int bitpos) {
  float ch = cosf(0.5f * t), sh = sinf(0.5f * t);
#pragma unroll
  for (int r = 0; r < 4; r++) {
    float ph = ((r >> bitpos) & 1) ? sh : -sh;  // imag part of row phase
#pragma unroll
    for (int c = 0; c < 4; c++) {
      float ar = mr[r][c], ai = mi[r][c];
      mr[r][c] = ch * ar - ph * ai;
      mi[r][c] = ch * ai + ph * ar;
    }
  }
}

// RY(t) on wire at bitpos: row pairs (bit=0 -> a, bit=1 -> b): a' = c*a - s*b ; b' = s*a + c*b
__device__ __forceinline__ void absorb_ry(float (&mr)[4][4], float (&mi)[4][4], float t, int bitpos) {
  float ch = cosf(0.5f * t), sh = sinf(0.5f * t);
#pragma unroll
  for (int r = 0; r < 4; r++) {
    if ((r >> bitpos) & 1) continue;
    int rb = r | (1 << bitpos);
#pragma unroll
    for (int c = 0; c < 4; c++) {
      float ar = mr[r][c], ai = mi[r][c];
      float br = mr[rb][c], bi = mi[rb][c];
      mr[r][c]  = ch * ar - sh * br;  mi[r][c]  = ch * ai - sh * bi;
      mr[rb][c] = sh * ar + ch * br;  mi[rb][c] = sh * ai + ch * bi;
    }
  }
}

// ws layout:
//   int   meta[64]        @ 0    : meta[0]=n_edges, meta[1+2e],meta[2+2e]=(i,j)
//   float Q1[8][8]        @ 256  : fused RZ*RY*RX per wire (2x2 complex, row-major re/im)
//   float E4[28][32]      @ 512  : fused edge 4x4 complex ((r*4+c)*2 + {re,im})
//   bf16  Ub[8][512][32]  @ 4096 : chunk ks holds k in [32ks,32ks+32); row m: 2r=Re,2r+1=Im
//                                  within row m (64B), 8-elem group sub at 16B slot (sub+(m>>1))&3

// ---------------- K0: edges (f64, exact numpy semantics) + gate fusion ----------------
__global__ __launch_bounds__(64) void prep_kernel(const float* __restrict__ wt,
                                                  const float* __restrict__ coup,
                                                  void* __restrict__ wsv) {
  const int lane = threadIdx.x;
  int* meta  = (int*)wsv;
  float* Q1  = (float*)((char*)wsv + 256);
  float* E4  = (float*)((char*)wsv + 512);

  double mn = 1e300, mx = -1e300;
  for (int k = 0; k < 64; k++) {
    double v = (double)coup[k];
    mn = v < mn ? v : mn;
    mx = v > mx ? v : mx;
  }
  int cnt = 0, myi = -1, myj = -1;
  for (int i = 0; i < 8; i++)
    for (int j = i + 1; j < 8; j++) {
      double cn = ((double)coup[i * 8 + j] - mn) / (mx - mn);
      if (cn > 0.5) {
        if (cnt == lane) { myi = i; myj = j; }
        cnt++;
      }
    }
  if (lane == 0) meta[0] = cnt;

  if (lane < 8) {
    // fused single-qubit: RZ(tz) * RY(ty) * RX(tx)
    float tx = wt[lane], ty = wt[8 + lane], tz = wt[16 + lane];
    float cx = cosf(0.5f * tx), sx = sinf(0.5f * tx);
    float cy = cosf(0.5f * ty), sy = sinf(0.5f * ty);
    float cz = cosf(0.5f * tz), sz = sinf(0.5f * tz);
    // M = RY*RX
    float m00r = cy * cx,  m00i = sy * sx;
    float m01r = -sy * cx, m01i = -cy * sx;
    float m10r = sy * cx,  m10i = -cy * sx;
    float m11r = cy * cx,  m11i = -sy * sx;
    // RZ: row0 *= (cz - i sz); row1 *= (cz + i sz)
    float* q = Q1 + lane * 8;
    q[0] = cz * m00r + sz * m00i; q[1] = cz * m00i - sz * m00r;
    q[2] = cz * m01r + sz * m01i; q[3] = cz * m01i - sz * m01r;
    q[4] = cz * m10r - sz * m10i; q[5] = cz * m10i + sz * m10r;
    q[6] = cz * m11r - sz * m11i; q[7] = cz * m11i + sz * m11r;
  }

  if (lane < cnt && lane < 28) {
    // fused edge block on pair basis b = 2*b_i + b_j (i=bitpos1/MSB, j=bitpos0/LSB)
    float mr[4][4], mi[4][4];
#pragma unroll
    for (int r = 0; r < 4; r++)
#pragma unroll
      for (int c = 0; c < 4; c++) { mr[r][c] = (r == c) ? 1.f : 0.f; mi[r][c] = 0.f; }

    bool nonadj = (myj - myi) != 1;
    int wb = 24 + 6 * lane;

    if (nonadj) rowswap4(mr, mi, 1, 2);       // SWAP
    // conv
    absorb_rz(mr, mi, -HP, 0);                // RZ(-pi/2) on j
    rowswap4(mr, mi, 1, 3);                   // CNOT ctrl=j tgt=i
    absorb_rz(mr, mi, wt[wb + 0], 1);         // RZ(p0) on i
    absorb_ry(mr, mi, wt[wb + 1], 0);         // RY(p1) on j
    rowswap4(mr, mi, 2, 3);                   // CNOT ctrl=i tgt=j
    absorb_ry(mr, mi, wt[wb + 2], 0);         // RY(p2) on j
    rowswap4(mr, mi, 1, 3);                   // CNOT ctrl=j tgt=i
    absorb_rz(mr, mi, HP, 1);                 // RZ(+pi/2) on i
    // pool
    absorb_rz(mr, mi, -HP, 0);
    rowswap4(mr, mi, 1, 3);
    absorb_rz(mr, mi, wt[wb + 3], 1);
    absorb_ry(mr, mi, wt[wb + 4], 0);
    rowswap4(mr, mi, 2, 3);
    absorb_ry(mr, mi, wt[wb + 5], 0);
    if (nonadj) rowswap4(mr, mi, 1, 2);       // SWAP back

    float* e = E4 + lane * 32;
#pragma unroll
    for (int r = 0; r < 4; r++)
#pragma unroll
      for (int c = 0; c < 4; c++) {
        e[(r * 4 + c) * 2]     = mr[r][c];
        e[(r * 4 + c) * 2 + 1] = mi[r][c];
      }
    meta[1 + 2 * lane] = myi;
    meta[2 + 2 * lane] = myj;
  }
}

// ---------------- K1: fused-gate basis-column simulation (~64 LDS steps) ----------------
__global__ __launch_bounds__(256) void build_u_kernel(const float* __restrict__ coup,
                                                      void* __restrict__ wsv) {
  const int* meta = (const int*)wsv;
  const float* Q1 = (const float*)((char*)wsv + 256);
  const float* E4 = (const float*)((char*)wsv + 512);
  unsigned char* Ub = (unsigned char*)wsv + 4096;

  const int c = blockIdx.x;
  const int tid = threadIdx.x;

  __shared__ float2 s[256];
  s[tid] = make_float2(tid == c ? 1.f : 0.f, 0.f);
  __syncthreads();

  // fused 1q per wire (wire w -> amplitude bit 7-w)
  for (int wi = 0; wi < 8; wi++) {
    const float* M = Q1 + wi * 8;
    int p = 7 - wi;
    float2 a0 = s[tid & ~(1 << p)];
    float2 a1 = s[tid | (1 << p)];
    int b = (tid >> p) & 1;
    float m0r = M[(b * 2 + 0) * 2], m0i = M[(b * 2 + 0) * 2 + 1];
    float m1r = M[(b * 2 + 1) * 2], m1i = M[(b * 2 + 1) * 2 + 1];
    float nr = m0r * a0.x - m0i * a0.y + m1r * a1.x - m1i * a1.y;
    float ni = m0r * a0.y + m0i * a0.x + m1r * a1.y + m1i * a1.x;
    __syncthreads();
    s[tid] = make_float2(nr, ni);
    __syncthreads();
  }

  // IsingXX on all pairs: new = cos*own + (-i sin)*flip_both
  for (int i = 0; i < 8; i++)
    for (int j = i + 1; j < 8; j++) {
      float t = coup[i * 8 + j];
      float ch = cosf(0.5f * t), sn = sinf(0.5f * t);
      int mask = (1 << (7 - i)) | (1 << (7 - j));
      float2 a = s[tid];
      float2 b = s[tid ^ mask];
      __syncthreads();
      s[tid] = make_float2(ch * a.x + sn * b.y, ch * a.y - sn * b.x);
      __syncthreads();
    }

  // fused edges
  int ne = meta[0];
  for (int e = 0; e < ne; e++) {
    int i = meta[1 + 2 * e], j = meta[2 + 2 * e];
    int p1 = 7 - i, p2 = 7 - j;
    int m1 = 1 << p1, m2 = 1 << p2;
    int b = ((tid >> p1) & 1) * 2 + ((tid >> p2) & 1);
    int base = tid & ~(m1 | m2);
    float2 a0 = s[base];
    float2 a1 = s[base | m2];
    float2 a2 = s[base | m1];
    float2 a3 = s[base | m1 | m2];
    const float* M = E4 + e * 32 + b * 8;
    float nr = M[0] * a0.x - M[1] * a0.y + M[2] * a1.x - M[3] * a1.y
             + M[4] * a2.x - M[5] * a2.y + M[6] * a3.x - M[7] * a3.y;
    float ni = M[0] * a0.y + M[1] * a0.x + M[2] * a1.y + M[3] * a1.x
             + M[4] * a2.y + M[5] * a2.x + M[6] * a3.y + M[7] * a3.x;
    __syncthreads();
    s[tid] = make_float2(nr, ni);
    __syncthreads();
  }

  // write column c as bf16 into the pre-swizzled chunk image (proven R5/R6)
  {
    int ks = c >> 5, kc = c & 31;
    int sub = kc >> 3, j2 = kc & 7;
    int p = (sub + tid) & 3;  // m>>1 == tid for both rows
    unsigned char* base = Ub + (size_t)ks * 32768 + (size_t)(2 * tid) * 64 + p * 16 + j2 * 2;
    *(unsigned short*)(base)      = f2bf(s[tid].x);
    *(unsigned short*)(base + 64) = f2bf(s[tid].y);
  }
}

// ---------------- K2: byte-identical to R6 (proven) ----------------
__global__ __launch_bounds__(512) void gemm_mfma16(const float* __restrict__ x,
                                                   const void* __restrict__ wsv,
                                                   float* __restrict__ out) {
  const unsigned char* Ub = (const unsigned char*)wsv + 4096;
  __shared__ __align__(16) unsigned char smem[65536];
  const int AOFF = 32768;

  const int tid = threadIdx.x;
  const int blk = blockIdx.x;
  const int wv = tid >> 6;
  const int lane = tid & 63;
  const int lm = lane & 15;
  const int lg = lane >> 4;

  {
    const int rl = tid >> 3;
    const int seg = tid & 7;
    const float4* xs = (const float4*)(x + (size_t)(blk * 64 + rl) * 256 + seg * 32);
    float4 v[8];
    float ss = 0.f;
#pragma unroll
    for (int i = 0; i < 8; i++) {
      v[i] = xs[i];
      ss += v[i].x * v[i].x + v[i].y * v[i].y + v[i].z * v[i].z + v[i].w * v[i].w;
    }
    ss += __shfl_xor(ss, 1);
    ss += __shfl_xor(ss, 2);
    ss += __shfl_xor(ss, 4);
    float inv = 1.0f / sqrtf(ss);
#pragma unroll
    for (int u = 0; u < 4; u++) {
      unsigned short h[8];
#pragma unroll
      for (int k = 0; k < 8; k++) {
        float f = ((const float*)v)[u * 8 + k] * inv;
        h[k] = f2bf(f);
      }
      uint4 pack;
      pack.x = (unsigned)h[0] | ((unsigned)h[1] << 16);
      pack.y = (unsigned)h[2] | ((unsigned)h[3] << 16);
      pack.z = (unsigned)h[4] | ((unsigned)h[5] << 16);
      pack.w = (unsigned)h[6] | ((unsigned)h[7] << 16);
      int byte = (rl * 512 + seg * 64 + u * 16) ^ ((rl & 7) << 4);
      *reinterpret_cast<uint4*>(&smem[byte]) = pack;
    }
  }

  f32x4 acc[4][4] = {};

  for (int ks = 0; ks < 8; ks++) {
    {
      const uint4* src = (const uint4*)(Ub + (size_t)ks * 32768);
#pragma unroll
      for (int g = 0; g < 4; g++)
        *reinterpret_cast<uint4*>(&smem[AOFF + g * 8192 + tid * 16]) = src[g * 512 + tid];
    }
    __syncthreads();

    sh4 a16[4][2], b16[4][2];
#pragma unroll
    for (int mf = 0; mf < 4; mf++) {
      const int m = wv * 64 + mf * 16 + lm;
#pragma unroll
      for (int h = 0; h < 2; h++) {
        int p = (2 * h + (lg >> 1) + (m >> 1)) & 3;
        a16[mf][h] = __builtin_bit_cast(sh4,
            *reinterpret_cast<const uint2*>(&smem[AOFF + m * 64 + p * 16 + (lg & 1) * 8]));
      }
    }
#pragma unroll
    for (int nf = 0; nf < 4; nf++) {
      const int n = nf * 16 + lm;
#pragma unroll
      for (int h = 0; h < 2; h++) {
        int byte = (n * 512 + ks * 64 + 32 * h + 8 * lg) ^ ((n & 7) << 4);
        b16[nf][h] = __builtin_bit_cast(sh4, *reinterpret_cast<const uint2*>(&smem[byte]));
      }
    }
#pragma unroll
    for (int mf = 0; mf < 4; mf++)
#pragma unroll
      for (int nf = 0; nf < 4; nf++) {
        acc[mf][nf] = __builtin_amdgcn_mfma_f32_16x16x16bf16_1k(a16[mf][0], b16[nf][0], acc[mf][nf], 0, 0, 0);
        acc[mf][nf] = __builtin_amdgcn_mfma_f32_16x16x16bf16_1k(a16[mf][1], b16[nf][1], acc[mf][nf], 0, 0, 0);
      }
    __syncthreads();
  }

  float pq[4][8];
#pragma unroll
  for (int nf = 0; nf < 4; nf++) {
    float T = 0.f, S7 = 0.f, S4 = 0.f, S3 = 0.f;
#pragma unroll
    for (int mf = 0; mf < 4; mf++) {
      f32x4 a = acc[mf][nf];
      float p0 = a[0] * a[0] + a[1] * a[1];
      float p1 = a[2] * a[2] + a[3] * a[3];
      float sp = p0 + p1, d = p0 - p1;
      T += sp;
      S7 += d;
      S4 += (mf & 1) ? -sp : sp;
      S3 += (mf & 2) ? -sp : sp;
    }
    pq[nf][7] = S7;
    pq[nf][6] = (lg & 1) ? -T : T;
    pq[nf][5] = (lg & 2) ? -T : T;
    pq[nf][4] = S4;
    pq[nf][3] = S3;
    pq[nf][2] = (wv & 1) ? -T : T;
    pq[nf][1] = (wv & 2) ? -T : T;
    pq[nf][0] = (wv & 4) ? -T : T;
  }
#pragma unroll
  for (int nf = 0; nf < 4; nf++)
#pragma unroll
    for (int k = 0; k < 8; k++) {
      pq[nf][k] += __shfl_xor(pq[nf][k], 16);
      pq[nf][k] += __shfl_xor(pq[nf][k], 32);
    }

  float* part = (float*)smem;  // [8][64][8]
  if (lg == 0) {
#pragma unroll
    for (int nf = 0; nf < 4; nf++) {
      float* dst = part + (wv * 64 + nf * 16 + lm) * 8;
#pragma unroll
      for (int k = 0; k < 8; k++) dst[k] = pq[nf][k];
    }
  }
  __syncthreads();
  {
    int b = tid >> 3, q = tid & 7;
    float v = 0.f;
#pragma unroll
    for (int w2 = 0; w2 < 8; w2++) v += part[(w2 * 64 + b) * 8 + q];
    out[(size_t)(blk * 64 + b) * 8 + q] = v;
  }
}

extern "C" void kernel_launch(void* const* d_in, const int* in_sizes, int n_in,
                              void* d_out, int out_size, void* d_ws, size_t ws_size,
                              hipStream_t stream) {
  const float* x    = (const float*)d_in[0];
  const float* wt   = (const float*)d_in[1];
  const float* coup = (const float*)d_in[2];
  float* out = (float*)d_out;

  prep_kernel<<<1, 64, 0, stream>>>(wt, coup, d_ws);
  build_u_kernel<<<256, 256, 0, stream>>>(coup, d_ws);
  gemm_mfma16<<<1024, 512, 0, stream>>>(x, d_ws, out);
}